// Round 1
// baseline (520.789 us; speedup 1.0000x reference)
//
#include <hip/hip_runtime.h>
#include <float.h>
#include <math.h>

// Problem constants (from reference setup_inputs)
#define B_ 4
#define N_ 4096
#define K_ 2048
#define TPB 256

// ws accumulator layout (floats):
// acc[0] = sum over (b,n) of min_m dist(pred,gt)     -> chamfer term 1
// acc[1] = sum over (b,m) of min_n dist(pred,gt)     -> chamfer term 2
// acc[2] = sum of relu(0.01 - knn_{1..4})            -> repulsion numerator
// acc[3] = sum of per-row knn16 variance             -> smoothness numerator
// acc[4] = sum over (b,k) of min_n dist(partial,pred)-> coverage numerator

__device__ inline float wave_sum(float v) {
#pragma unroll
  for (int off = 32; off > 0; off >>= 1) v += __shfl_down(v, off, 64);
  return v;
}

// scratch must hold >= 4 floats; aliases the cols LDS array (safe: synced)
__device__ inline float block_sum(float v, float* scratch) {
  const int lane = threadIdx.x & 63;
  const int wid  = threadIdx.x >> 6;
  v = wave_sum(v);
  __syncthreads();
  if (lane == 0) scratch[wid] = v;
  __syncthreads();
  float r = 0.f;
  if (wid == 0) {
    r = (lane < (TPB / 64)) ? scratch[lane] : 0.f;
    r = wave_sum(r);
  }
  __syncthreads();
  return r;  // valid in thread 0 only
}

__global__ void zero_acc(float* acc) {
  if (threadIdx.x < 8) acc[threadIdx.x] = 0.f;
}

// Block roles:
//  [0,64)    role 0: rows = pred, cols = gt    -> acc[0]
//  [64,128)  role 1: rows = gt,   cols = pred  -> acc[1]
//  [128,160) role 2: rows = partial, cols = pred -> acc[4]
//  [160,224) role 3: rows = pred, cols = pred  -> top-16 -> acc[2], acc[3]
__global__ __launch_bounds__(TPB) void fused_loss(const float* __restrict__ pred,
                                                  const float* __restrict__ gt,
                                                  const float* __restrict__ partial,
                                                  float* __restrict__ acc) {
  __shared__ float4 cols[N_];           // 64 KB, exactly at the static LDS cap
  float* scratch = (float*)cols;        // reused for reduction after main loop

  const int blk = blockIdx.x;
  int role, rel;
  if (blk < 64)       { role = 0; rel = blk; }
  else if (blk < 128) { role = 1; rel = blk - 64; }
  else if (blk < 160) { role = 2; rel = blk - 128; }
  else                { role = 3; rel = blk - 160; }

  const int blocksPerBatch = (role == 2) ? (K_ / TPB) : (N_ / TPB);
  const int b    = rel / blocksPerBatch;
  const int row0 = (rel % blocksPerBatch) * TPB;

  // ---- stage column cloud into LDS (float4-padded for ds_read_b128) ----
  const float* colsrc = (role == 0) ? gt : pred;
  const size_t cbase = (size_t)b * N_ * 3;
  for (int i = threadIdx.x; i < N_; i += TPB) {
    float x = colsrc[cbase + 3 * i + 0];
    float y = colsrc[cbase + 3 * i + 1];
    float z = colsrc[cbase + 3 * i + 2];
    cols[i] = make_float4(x, y, z, 0.f);
  }
  __syncthreads();

  // ---- my row point ----
  const float* rowsrc = (role == 1) ? gt : (role == 2) ? partial : pred;
  const int rowsPerBatch = (role == 2) ? K_ : N_;
  const int r = row0 + threadIdx.x;
  const size_t rbase = ((size_t)b * rowsPerBatch + r) * 3;
  const float px = rowsrc[rbase + 0];
  const float py = rowsrc[rbase + 1];
  const float pz = rowsrc[rbase + 2];

  if (role != 3) {
    // min over all columns; 4 independent accumulators break the fmin chain
    float m0 = FLT_MAX, m1 = FLT_MAX, m2 = FLT_MAX, m3 = FLT_MAX;
    for (int j = 0; j < N_; j += 4) {
      float4 c0 = cols[j + 0];
      float4 c1 = cols[j + 1];
      float4 c2 = cols[j + 2];
      float4 c3 = cols[j + 3];
      float dx0 = px - c0.x, dy0 = py - c0.y, dz0 = pz - c0.z;
      float dx1 = px - c1.x, dy1 = py - c1.y, dz1 = pz - c1.z;
      float dx2 = px - c2.x, dy2 = py - c2.y, dz2 = pz - c2.z;
      float dx3 = px - c3.x, dy3 = py - c3.y, dz3 = pz - c3.z;
      float s0 = fmaf(dx0, dx0, fmaf(dy0, dy0, dz0 * dz0));
      float s1 = fmaf(dx1, dx1, fmaf(dy1, dy1, dz1 * dz1));
      float s2 = fmaf(dx2, dx2, fmaf(dy2, dy2, dz2 * dz2));
      float s3 = fmaf(dx3, dx3, fmaf(dy3, dy3, dz3 * dz3));
      m0 = fminf(m0, s0);
      m1 = fminf(m1, s1);
      m2 = fminf(m2, s2);
      m3 = fminf(m3, s3);
    }
    float mins = fminf(fminf(m0, m1), fminf(m2, m3));
    float d = sqrtf(fmaxf(mins, 1e-12f));
    float tot = block_sum(d, scratch);
    if (threadIdx.x == 0) {
      atomicAdd(&acc[(role == 2) ? 4 : role], tot);
    }
  } else {
    // top-16 smallest squared distances (sorted ascending, in registers)
    float t16[16];
#pragma unroll
    for (int i = 0; i < 16; i++) t16[i] = FLT_MAX;

#pragma unroll 4
    for (int j = 0; j < N_; j++) {
      float4 c = cols[j];
      float dx = px - c.x, dy = py - c.y, dz = pz - c.z;
      float s = fmaf(dx, dx, fmaf(dy, dy, dz * dz));
      if (s < t16[15]) {
        float v = s;
#pragma unroll
        for (int i = 0; i < 16; i++) {
          float lo = fminf(t16[i], v);
          v = fmaxf(t16[i], v);
          t16[i] = lo;
        }
      }
    }

    // distances (self pair -> sqrt(EPS) = 1e-6, rank 0)
    float d[16];
    float sum = 0.f;
#pragma unroll
    for (int i = 0; i < 16; i++) {
      d[i] = sqrtf(fmaxf(t16[i], 1e-12f));
      sum += d[i];
    }
    const float mean = sum * (1.f / 16.f);
    float var = 0.f;
#pragma unroll
    for (int i = 0; i < 16; i++) {
      float e = d[i] - mean;
      var = fmaf(e, e, var);
    }
    var *= (1.f / 15.f);  // unbiased

    // repulsion: ranks 1..4 (rank 0 = self), relu(0.01 - d)
    float repc = 0.f;
#pragma unroll
    for (int i = 1; i <= 4; i++) repc += fmaxf(0.01f - d[i], 0.f);

    float t_rep = block_sum(repc, scratch);
    float t_var = block_sum(var, scratch);
    if (threadIdx.x == 0) {
      atomicAdd(&acc[2], t_rep);
      atomicAdd(&acc[3], t_var);
    }
  }
}

__global__ void finalize(const float* __restrict__ acc, float* __restrict__ out) {
  if (threadIdx.x == 0 && blockIdx.x == 0) {
    const float cd     = acc[0] / (float)(B_ * N_) + acc[1] / (float)(B_ * N_);
    const float rep    = acc[2] / (float)(B_ * N_ * 4);
    const float smooth = acc[3] / (float)(B_ * N_);
    const float cov    = acc[4] / (float)(B_ * K_);
    const float total  = 1.0f * cd + 0.01f * rep + 0.005f * smooth + 0.1f * cov;
    out[0] = total;
    out[1] = cd;
    out[2] = rep;
    out[3] = smooth;
    out[4] = cov;
  }
}

extern "C" void kernel_launch(void* const* d_in, const int* in_sizes, int n_in,
                              void* d_out, int out_size, void* d_ws, size_t ws_size,
                              hipStream_t stream) {
  const float* pred    = (const float*)d_in[0];  // [4,4096,3]
  const float* gt      = (const float*)d_in[1];  // [4,4096,3]
  const float* partial = (const float*)d_in[2];  // [4,2048,3]
  float* out = (float*)d_out;                    // 5 scalars
  float* acc = (float*)d_ws;                     // >= 8 floats

  zero_acc<<<1, 64, 0, stream>>>(acc);
  fused_loss<<<224, TPB, 0, stream>>>(pred, gt, partial, acc);
  finalize<<<1, 64, 0, stream>>>(acc, out);
}

// Round 2
// 213.229 us; speedup vs baseline: 2.4424x; 2.4424x over previous
//
#include <hip/hip_runtime.h>
#include <float.h>
#include <math.h>

// Problem constants (from reference setup_inputs)
#define B_ 4
#define N_ 4096
#define K_ 2048
#define TPB 256

// ws accumulator layout (floats):
// acc[0] = sum_{b,n} min_m dist(pred,gt)      -> chamfer term 1
// acc[1] = sum_{b,m} min_n dist(pred,gt)      -> chamfer term 2
// acc[2] = sum relu(0.01 - knn_{1..4})        -> repulsion numerator
// acc[3] = sum per-row knn16 variance         -> smoothness numerator
// acc[4] = sum_{b,k} min_n dist(partial,pred) -> coverage numerator

__device__ inline float wave_sum(float v) {
#pragma unroll
  for (int off = 32; off > 0; off >>= 1) v += __shfl_down(v, off, 64);
  return v;
}

// sorted-ascending 16-element min-list insertion (branchless bubble)
__device__ inline void insert16(float (&t)[16], float s) {
  float v = s;
#pragma unroll
  for (int i = 0; i < 16; i++) {
    float lo = fminf(t[i], v);
    v = fmaxf(t[i], v);
    t[i] = lo;
  }
}

__global__ void zero_acc(float* acc) {
  if (threadIdx.x < 8) acc[threadIdx.x] = 0.f;
}

// Block roles (grid = 1152):
//  [0,256)     role 0: rows=pred, cols=gt     -> acc[0]   (64 rows/block, 2 rows/thread)
//  [256,512)   role 1: rows=gt,   cols=pred   -> acc[1]   (64 rows/block)
//  [512,640)   role 2: rows=partial, cols=pred-> acc[4]   (64 rows/block)
//  [640,1152)  role 3: rows=pred, cols=pred, top-16 -> acc[2],acc[3] (32 rows/block, 1 row/thread)
// Thread (r,g) = (t&31, t>>5): 8-way column split; per 1024-col tile each
// thread scans slice [g*128, g*128+128) -> 512 cols/thread over 4 tiles.
__global__ __launch_bounds__(TPB, 4) void fused_loss(const float* __restrict__ pred,
                                                     const float* __restrict__ gt,
                                                     const float* __restrict__ partial,
                                                     float* __restrict__ acc) {
  // union: tile staging (1024 float4 = 16 KB) / role-3 merge lists
  // (32*8*17 floats = 17 KB, stride 17 breaks bank aliasing) / min-merge (64*9)
  __shared__ __align__(16) float smem_f[4352];
  float4* tile = reinterpret_cast<float4*>(smem_f);

  const int blk = blockIdx.x;
  int role, rel;
  if (blk < 256)      { role = 0; rel = blk; }
  else if (blk < 512) { role = 1; rel = blk - 256; }
  else if (blk < 640) { role = 2; rel = blk - 512; }
  else                { role = 3; rel = blk - 640; }

  const int t = threadIdx.x;
  const int r = t & 31;
  const int g = t >> 5;

  int b, row0;
  if (role == 3)      { b = rel >> 7; row0 = (rel & 127) * 32; }  // 128 blocks/batch
  else if (role == 2) { b = rel >> 5; row0 = (rel & 31) * 64; }   // 32 blocks/batch
  else                { b = rel >> 6; row0 = (rel & 63) * 64; }   // 64 blocks/batch

  const float* colsrc = (role == 0) ? gt : pred;
  const size_t cbase = (size_t)b * N_ * 3;

  const float* rowsrc = (role == 1) ? gt : (role == 2) ? partial : pred;
  const int rowsPerBatch = (role == 2) ? K_ : N_;

  // row A (all roles); row B (min roles only — role 3 would index OOB)
  const int rA = row0 + r;
  const size_t rbA = ((size_t)b * rowsPerBatch + rA) * 3;
  const float ax = rowsrc[rbA + 0], ay = rowsrc[rbA + 1], az = rowsrc[rbA + 2];
  float bx = 0.f, by = 0.f, bz = 0.f;
  if (role != 3) {
    const size_t rbB = ((size_t)b * rowsPerBatch + (row0 + 32 + r)) * 3;
    bx = rowsrc[rbB + 0]; by = rowsrc[rbB + 1]; bz = rowsrc[rbB + 2];
  }

  // accumulators: 8 independent fmin chains (min roles) or sorted top-16 (role 3)
  float mA0 = FLT_MAX, mA1 = FLT_MAX, mA2 = FLT_MAX, mA3 = FLT_MAX;
  float mB0 = FLT_MAX, mB1 = FLT_MAX, mB2 = FLT_MAX, mB3 = FLT_MAX;
  float t16[16];
#pragma unroll
  for (int i = 0; i < 16; i++) t16[i] = FLT_MAX;

  const int base = g * 128;

  for (int T = 0; T < 4; ++T) {
    __syncthreads();  // previous tile fully consumed
    {
      const int c0 = T * 1024;
      for (int i = t; i < 1024; i += TPB) {
        const size_t p = cbase + 3 * (size_t)(c0 + i);
        tile[i] = make_float4(colsrc[p], colsrc[p + 1], colsrc[p + 2], 0.f);
      }
    }
    __syncthreads();

    if (role != 3) {
      for (int j = 0; j < 128; j += 4) {
        float4 c0 = tile[base + j + 0];
        float4 c1 = tile[base + j + 1];
        float4 c2 = tile[base + j + 2];
        float4 c3 = tile[base + j + 3];
        {
          float dx = ax - c0.x, dy = ay - c0.y, dz = az - c0.z;
          mA0 = fminf(mA0, fmaf(dx, dx, fmaf(dy, dy, dz * dz)));
        }
        {
          float dx = ax - c1.x, dy = ay - c1.y, dz = az - c1.z;
          mA1 = fminf(mA1, fmaf(dx, dx, fmaf(dy, dy, dz * dz)));
        }
        {
          float dx = ax - c2.x, dy = ay - c2.y, dz = az - c2.z;
          mA2 = fminf(mA2, fmaf(dx, dx, fmaf(dy, dy, dz * dz)));
        }
        {
          float dx = ax - c3.x, dy = ay - c3.y, dz = az - c3.z;
          mA3 = fminf(mA3, fmaf(dx, dx, fmaf(dy, dy, dz * dz)));
        }
        {
          float dx = bx - c0.x, dy = by - c0.y, dz = bz - c0.z;
          mB0 = fminf(mB0, fmaf(dx, dx, fmaf(dy, dy, dz * dz)));
        }
        {
          float dx = bx - c1.x, dy = by - c1.y, dz = bz - c1.z;
          mB1 = fminf(mB1, fmaf(dx, dx, fmaf(dy, dy, dz * dz)));
        }
        {
          float dx = bx - c2.x, dy = by - c2.y, dz = bz - c2.z;
          mB2 = fminf(mB2, fmaf(dx, dx, fmaf(dy, dy, dz * dz)));
        }
        {
          float dx = bx - c3.x, dy = by - c3.y, dz = bz - c3.z;
          mB3 = fminf(mB3, fmaf(dx, dx, fmaf(dy, dy, dz * dz)));
        }
      }
    } else {
#pragma unroll 4
      for (int j = 0; j < 128; ++j) {
        float4 c = tile[base + j];
        float dx = ax - c.x, dy = ay - c.y, dz = az - c.z;
        float s = fmaf(dx, dx, fmaf(dy, dy, dz * dz));
        if (s < t16[15]) insert16(t16, s);
      }
    }
  }

  if (role != 3) {
    const float mA = fminf(fminf(mA0, mA1), fminf(mA2, mA3));
    const float mB = fminf(fminf(mB0, mB1), fminf(mB2, mB3));
    __syncthreads();
    smem_f[(r)      * 9 + g] = mA;   // stride 9: bank-spread
    smem_f[(r + 32) * 9 + g] = mB;
    __syncthreads();
    if (t < 64) {  // wave 0: one row per lane
      float m = FLT_MAX;
#pragma unroll
      for (int k = 0; k < 8; ++k) m = fminf(m, smem_f[t * 9 + k]);
      float d = sqrtf(fmaxf(m, 1e-12f));
      d = wave_sum(d);
      if (t == 0) atomicAdd(&acc[(role == 2) ? 4 : role], d);
    }
  } else {
    __syncthreads();
#pragma unroll
    for (int i = 0; i < 16; i++) smem_f[(r * 8 + g) * 17 + i] = t16[i];
    __syncthreads();
    float repc = 0.f, varc = 0.f;
    if (t < 32) {  // one merge thread per row
      float f16[16];
#pragma unroll
      for (int i = 0; i < 16; i++) f16[i] = FLT_MAX;
      for (int g2 = 0; g2 < 8; ++g2) {
        const float* L = &smem_f[(t * 8 + g2) * 17];
        for (int i = 0; i < 16; ++i) {
          float s = L[i];
          if (s >= f16[15]) break;  // lists ascending: rest can't qualify
          insert16(f16, s);
        }
      }
      float d16[16];
      float sum = 0.f;
#pragma unroll
      for (int i = 0; i < 16; i++) {
        d16[i] = sqrtf(fmaxf(f16[i], 1e-12f));  // self pair -> 1e-6, rank 0
        sum += d16[i];
      }
      const float mean = sum * 0.0625f;
      float var = 0.f;
#pragma unroll
      for (int i = 0; i < 16; i++) {
        float e = d16[i] - mean;
        var = fmaf(e, e, var);
      }
      varc = var * (1.f / 15.f);  // unbiased
#pragma unroll
      for (int i = 1; i <= 4; i++) repc += fmaxf(0.01f - d16[i], 0.f);
    }
    if (t < 64) {  // wave 0 reduces (lanes 32-63 contribute 0)
      repc = wave_sum(repc);
      varc = wave_sum(varc);
      if (t == 0) {
        atomicAdd(&acc[2], repc);
        atomicAdd(&acc[3], varc);
      }
    }
  }
}

__global__ void finalize(const float* __restrict__ acc, float* __restrict__ out) {
  if (threadIdx.x == 0 && blockIdx.x == 0) {
    const float cd     = acc[0] / (float)(B_ * N_) + acc[1] / (float)(B_ * N_);
    const float rep    = acc[2] / (float)(B_ * N_ * 4);
    const float smooth = acc[3] / (float)(B_ * N_);
    const float cov    = acc[4] / (float)(B_ * K_);
    const float total  = 1.0f * cd + 0.01f * rep + 0.005f * smooth + 0.1f * cov;
    out[0] = total;
    out[1] = cd;
    out[2] = rep;
    out[3] = smooth;
    out[4] = cov;
  }
}

extern "C" void kernel_launch(void* const* d_in, const int* in_sizes, int n_in,
                              void* d_out, int out_size, void* d_ws, size_t ws_size,
                              hipStream_t stream) {
  const float* pred    = (const float*)d_in[0];  // [4,4096,3]
  const float* gt      = (const float*)d_in[1];  // [4,4096,3]
  const float* partial = (const float*)d_in[2];  // [4,2048,3]
  float* out = (float*)d_out;                    // 5 scalars
  float* acc = (float*)d_ws;                     // >= 8 floats

  zero_acc<<<1, 64, 0, stream>>>(acc);
  fused_loss<<<1152, TPB, 0, stream>>>(pred, gt, partial, acc);
  finalize<<<1, 64, 0, stream>>>(acc, out);
}

// Round 3
// 125.113 us; speedup vs baseline: 4.1625x; 1.7043x over previous
//
#include <hip/hip_runtime.h>
#include <float.h>
#include <math.h>

// Problem constants (from reference setup_inputs)
#define B_ 4
#define N_ 4096
#define K_ 2048
#define TPB 256

// ws accumulator layout (floats):
// acc[0] = sum_{b,n} min_m dist(pred,gt)      -> chamfer term 1
// acc[1] = sum_{b,m} min_n dist(pred,gt)      -> chamfer term 2
// acc[2] = sum relu(0.01 - knn_{1..4})        -> repulsion numerator
// acc[3] = sum per-row knn16 variance         -> smoothness numerator
// acc[4] = sum_{b,k} min_n dist(partial,pred) -> coverage numerator

__device__ inline float wave_sum(float v) {
#pragma unroll
  for (int off = 32; off > 0; off >>= 1) v += __shfl_down(v, off, 64);
  return v;
}

__device__ inline void ce_asc(float& a, float& b) {
  float lo = fminf(a, b), hi = fmaxf(a, b);
  a = lo; b = hi;
}
__device__ inline void ce_desc(float& a, float& b) {
  float lo = fminf(a, b), hi = fmaxf(a, b);
  a = hi; b = lo;
}

// Fully-unrolled bitonic sort of 16 values, DESCENDING (80 CEs).
__device__ inline void sort16_desc(float (&v)[16]) {
#pragma unroll
  for (int k = 2; k <= 16; k <<= 1) {
#pragma unroll
    for (int j = k >> 1; j > 0; j >>= 1) {
#pragma unroll
      for (int i = 0; i < 16; ++i) {
        int ixj = i ^ j;
        if (ixj > i) {
          if ((i & k) == 0) ce_desc(v[i], v[ixj]);
          else              ce_asc(v[i], v[ixj]);
        }
      }
    }
  }
}

// t ascending (running top-16), c DESCENDING (new batch).
// Half-cleaner keeps the 16 smallest (bitonic), then bitonic-merge ascending.
__device__ inline void merge16(float (&t)[16], const float (&c)[16]) {
#pragma unroll
  for (int i = 0; i < 16; ++i) t[i] = fminf(t[i], c[i]);
#pragma unroll
  for (int j = 8; j > 0; j >>= 1) {
#pragma unroll
    for (int i = 0; i < 16; ++i) {
      int ixj = i ^ j;
      if (ixj > i) ce_asc(t[i], t[ixj]);
    }
  }
}

// sorted-ascending 16-element min-list insertion (merge phase only)
__device__ inline void insert16(float (&t)[16], float s) {
  float v = s;
#pragma unroll
  for (int i = 0; i < 16; i++) {
    float lo = fminf(t[i], v);
    v = fmaxf(t[i], v);
    t[i] = lo;
  }
}

__global__ void zero_acc(float* acc) {
  if (threadIdx.x < 8) acc[threadIdx.x] = 0.f;
}

// Block roles (grid = 1152), role 3 (longest) FIRST for load balance:
//  [0,512)     role 3: rows=pred, cols=pred, top-16 -> acc[2],acc[3] (32 rows/block)
//  [512,768)   role 0: rows=pred, cols=gt     -> acc[0]   (64 rows/block, 2/thread)
//  [768,1024)  role 1: rows=gt,   cols=pred   -> acc[1]
//  [1024,1152) role 2: rows=partial, cols=pred-> acc[4]
// Thread (r,g) = (t&31, t>>5): 8-way column split; per 1024-col tile each
// thread scans slice [g*128, g*128+128) -> 512 cols/thread over 4 tiles.
// LDS tile holds (x, y, z, |c|^2); distances via s' = |c|^2 - 2 a.c (3 fma),
// |a|^2 added after selection (monotone shift).
__global__ __launch_bounds__(TPB, 4) void fused_loss(const float* __restrict__ pred,
                                                     const float* __restrict__ gt,
                                                     const float* __restrict__ partial,
                                                     float* __restrict__ acc) {
  // union: tile staging (1024 float4 = 16 KB) / role-3 merge lists
  // (32*8*17 floats, stride 17) / min-merge (64*9)
  __shared__ __align__(16) float smem_f[4352];
  float4* tile = reinterpret_cast<float4*>(smem_f);

  const int blk = blockIdx.x;
  int role, rel;
  if (blk < 512)       { role = 3; rel = blk; }
  else if (blk < 768)  { role = 0; rel = blk - 512; }
  else if (blk < 1024) { role = 1; rel = blk - 768; }
  else                 { role = 2; rel = blk - 1024; }

  const int t = threadIdx.x;
  const int r = t & 31;
  const int g = t >> 5;

  int b, row0;
  if (role == 3)      { b = rel >> 7; row0 = (rel & 127) * 32; }  // 128 blocks/batch
  else if (role == 2) { b = rel >> 5; row0 = (rel & 31) * 64; }   // 32 blocks/batch
  else                { b = rel >> 6; row0 = (rel & 63) * 64; }   // 64 blocks/batch

  const float* colsrc = (role == 0) ? gt : pred;
  const size_t cbase = (size_t)b * N_ * 3;

  const float* rowsrc = (role == 1) ? gt : (role == 2) ? partial : pred;
  const int rowsPerBatch = (role == 2) ? K_ : N_;

  // row A (all roles); row B (min roles only)
  const int rA = row0 + r;
  const size_t rbA = ((size_t)b * rowsPerBatch + rA) * 3;
  const float ax = rowsrc[rbA + 0], ay = rowsrc[rbA + 1], az = rowsrc[rbA + 2];
  const float aaA = fmaf(ax, ax, fmaf(ay, ay, az * az));
  const float nax = -2.f * ax, nay = -2.f * ay, naz = -2.f * az;
  float nbx = 0.f, nby = 0.f, nbz = 0.f, aaB = 0.f;
  if (role != 3) {
    const size_t rbB = ((size_t)b * rowsPerBatch + (row0 + 32 + r)) * 3;
    const float px = rowsrc[rbB + 0], py = rowsrc[rbB + 1], pz = rowsrc[rbB + 2];
    aaB = fmaf(px, px, fmaf(py, py, pz * pz));
    nbx = -2.f * px; nby = -2.f * py; nbz = -2.f * pz;
  }

  // accumulators: 8 independent fmin chains (min roles) or ascending top-16 (role 3)
  float mA0 = FLT_MAX, mA1 = FLT_MAX, mA2 = FLT_MAX, mA3 = FLT_MAX;
  float mB0 = FLT_MAX, mB1 = FLT_MAX, mB2 = FLT_MAX, mB3 = FLT_MAX;
  float t16[16];
#pragma unroll
  for (int i = 0; i < 16; i++) t16[i] = FLT_MAX;

  const int base = g * 128;

  for (int T = 0; T < 4; ++T) {
    __syncthreads();  // previous tile fully consumed
    {
      const int c0 = T * 1024;
      for (int i = t; i < 1024; i += TPB) {
        const size_t p = cbase + 3 * (size_t)(c0 + i);
        const float x = colsrc[p], y = colsrc[p + 1], z = colsrc[p + 2];
        tile[i] = make_float4(x, y, z, fmaf(x, x, fmaf(y, y, z * z)));
      }
    }
    __syncthreads();

    if (role != 3) {
      for (int j = 0; j < 128; j += 4) {
        float4 c0 = tile[base + j + 0];
        float4 c1 = tile[base + j + 1];
        float4 c2 = tile[base + j + 2];
        float4 c3 = tile[base + j + 3];
        mA0 = fminf(mA0, fmaf(nax, c0.x, fmaf(nay, c0.y, fmaf(naz, c0.z, c0.w))));
        mA1 = fminf(mA1, fmaf(nax, c1.x, fmaf(nay, c1.y, fmaf(naz, c1.z, c1.w))));
        mA2 = fminf(mA2, fmaf(nax, c2.x, fmaf(nay, c2.y, fmaf(naz, c2.z, c2.w))));
        mA3 = fminf(mA3, fmaf(nax, c3.x, fmaf(nay, c3.y, fmaf(naz, c3.z, c3.w))));
        mB0 = fminf(mB0, fmaf(nbx, c0.x, fmaf(nby, c0.y, fmaf(nbz, c0.z, c0.w))));
        mB1 = fminf(mB1, fmaf(nbx, c1.x, fmaf(nby, c1.y, fmaf(nbz, c1.z, c1.w))));
        mB2 = fminf(mB2, fmaf(nbx, c2.x, fmaf(nby, c2.y, fmaf(nbz, c2.z, c2.w))));
        mB3 = fminf(mB3, fmaf(nbx, c3.x, fmaf(nby, c3.y, fmaf(nbz, c3.z, c3.w))));
      }
    } else {
      for (int jg = 0; jg < 128; jg += 16) {
        float c16[16];
#pragma unroll
        for (int u = 0; u < 16; ++u) {
          float4 c = tile[base + jg + u];
          c16[u] = fmaf(nax, c.x, fmaf(nay, c.y, fmaf(naz, c.z, c.w)));
        }
        sort16_desc(c16);
        merge16(t16, c16);
      }
    }
  }

  if (role != 3) {
    const float mA = fminf(fminf(mA0, mA1), fminf(mA2, mA3)) + aaA;
    const float mB = fminf(fminf(mB0, mB1), fminf(mB2, mB3)) + aaB;
    __syncthreads();
    smem_f[(r)      * 9 + g] = mA;   // stride 9: bank-spread
    smem_f[(r + 32) * 9 + g] = mB;
    __syncthreads();
    if (t < 64) {  // wave 0: one row per lane
      float m = FLT_MAX;
#pragma unroll
      for (int k = 0; k < 8; ++k) m = fminf(m, smem_f[t * 9 + k]);
      float d = sqrtf(fmaxf(m, 1e-12f));
      d = wave_sum(d);
      if (t == 0) atomicAdd(&acc[(role == 2) ? 4 : role], d);
    }
  } else {
    __syncthreads();
#pragma unroll
    for (int i = 0; i < 16; i++) smem_f[(r * 8 + g) * 17 + i] = t16[i];
    __syncthreads();
    float repc = 0.f, varc = 0.f;
    if (t < 32) {  // one merge thread per row
      float f16[16];
#pragma unroll
      for (int i = 0; i < 16; i++) f16[i] = FLT_MAX;
      for (int g2 = 0; g2 < 8; ++g2) {
        const float* L = &smem_f[(t * 8 + g2) * 17];
        for (int i = 0; i < 16; ++i) {
          float s = L[i];
          if (s >= f16[15]) break;  // lists ascending: rest can't qualify
          insert16(f16, s);
        }
      }
      float d16[16];
      float sum = 0.f;
#pragma unroll
      for (int i = 0; i < 16; i++) {
        // add |a|^2 back; self pair -> ~0 -> clamped -> 1e-6
        d16[i] = sqrtf(fmaxf(f16[i] + aaA, 1e-12f));
        sum += d16[i];
      }
      const float mean = sum * 0.0625f;
      float var = 0.f;
#pragma unroll
      for (int i = 0; i < 16; i++) {
        float e = d16[i] - mean;
        var = fmaf(e, e, var);
      }
      varc = var * (1.f / 15.f);  // unbiased
#pragma unroll
      for (int i = 1; i <= 4; i++) repc += fmaxf(0.01f - d16[i], 0.f);
    }
    if (t < 64) {  // wave 0 reduces (lanes 32-63 contribute 0)
      repc = wave_sum(repc);
      varc = wave_sum(varc);
      if (t == 0) {
        atomicAdd(&acc[2], repc);
        atomicAdd(&acc[3], varc);
      }
    }
  }
}

__global__ void finalize(const float* __restrict__ acc, float* __restrict__ out) {
  if (threadIdx.x == 0 && blockIdx.x == 0) {
    const float cd     = acc[0] / (float)(B_ * N_) + acc[1] / (float)(B_ * N_);
    const float rep    = acc[2] / (float)(B_ * N_ * 4);
    const float smooth = acc[3] / (float)(B_ * N_);
    const float cov    = acc[4] / (float)(B_ * K_);
    const float total  = 1.0f * cd + 0.01f * rep + 0.005f * smooth + 0.1f * cov;
    out[0] = total;
    out[1] = cd;
    out[2] = rep;
    out[3] = smooth;
    out[4] = cov;
  }
}

extern "C" void kernel_launch(void* const* d_in, const int* in_sizes, int n_in,
                              void* d_out, int out_size, void* d_ws, size_t ws_size,
                              hipStream_t stream) {
  const float* pred    = (const float*)d_in[0];  // [4,4096,3]
  const float* gt      = (const float*)d_in[1];  // [4,4096,3]
  const float* partial = (const float*)d_in[2];  // [4,2048,3]
  float* out = (float*)d_out;                    // 5 scalars
  float* acc = (float*)d_ws;                     // >= 8 floats

  zero_acc<<<1, 64, 0, stream>>>(acc);
  fused_loss<<<1152, TPB, 0, stream>>>(pred, gt, partial, acc);
  finalize<<<1, 64, 0, stream>>>(acc, out);
}